// Round 10
// baseline (153.516 us; speedup 1.0000x reference)
//
#include <hip/hip_runtime.h>
#include <hip/hip_bf16.h>

// Problem constants (GCN_66649302499531)
#define NN 20000
#define NG 400
#define D_IN 128
#define H1 256
#define H2 256
#define D_OUT 128
#define WT_ELEMS (D_IN * H1 + H1 * H2 + H2 * D_OUT)   // 131072
#define MC2 512     // per-group member cap (mean 50; max ~100)
#define WSLOT 256   // per-wave slice scratch cap (slice mean 6.25)

// LDS strides (elements)
#define STY 72      // Yt feat-major: 256 x 72 bf16 (64 nodes + 8 pad)
#define ST1 136     // T1 node-major: 64 x 128 bf16 (+8 pad)
#define ST2 264     // T2 node-major: 64 x 256 bf16 (+8 pad)
#define ST3 264     // T3 node-major
#define SF  132     // F  node-major: 64 x 128 fp32 (+4 pad)
#define REGB 36864
#define PIPEB (2 * REGB)   // per-pipeline: RA | RB ping-pong

typedef __attribute__((ext_vector_type(8))) short short8;
typedef __attribute__((ext_vector_type(4))) short short4v;
typedef __attribute__((ext_vector_type(4))) float floatx4;

__device__ __forceinline__ short f2b(float f) {
    __hip_bfloat16 h = __float2bfloat16(f);
    return *(short*)&h;
}

// ---------------------------------------------------------------------------
// Weight transposes fp32 [K][N] -> bf16 [N][K], one launch.
// ---------------------------------------------------------------------------

__global__ __launch_bounds__(256) void wt_all(
    const float* __restrict__ W1, const float* __restrict__ W2,
    const float* __restrict__ W3, __hip_bfloat16* __restrict__ Wt1,
    __hip_bfloat16* __restrict__ Wt2, __hip_bfloat16* __restrict__ Wt3)
{
    int o = blockIdx.x * 256 + threadIdx.x;
    if (o < D_IN * H1) {
        int n = o / D_IN, k = o - n * D_IN;
        Wt1[o] = __float2bfloat16(W1[(size_t)k * H1 + n]);
    } else if (o < D_IN * H1 + H1 * H2) {
        int p = o - D_IN * H1;
        int n = p / H1, k = p - n * H1;
        Wt2[p] = __float2bfloat16(W2[(size_t)k * H2 + n]);
    } else if (o < WT_ELEMS) {
        int p = o - D_IN * H1 - H1 * H2;
        int n = p / H2, k = p - n * H2;
        Wt3[p] = __float2bfloat16(W3[(size_t)k * D_OUT + n]);
    }
}

// ---------------------------------------------------------------------------
// R25 = R24 retry after infra failure, with the attribute in its minimal
// form: amdgpu_waves_per_eu(4) (min only, no exact-pin max). min=4 waves/EU
// caps the allocator at 512/4 = 128 VGPR — enough for the ~100-VGPR body,
// killing the spills that confounded R22 ((1024,4) -> 64 VGPR) and R23
// (plain (1024) -> 64 VGPR). Body is byte-identical to the PASSING R23:
// two parallel 8-wave R17 pipelines per 1024-thread block, grid 200.
// Tests dispatch ~= Nwg/r + L (launch-rate model).
// ---------------------------------------------------------------------------

__global__ __attribute__((amdgpu_flat_work_group_size(1024, 1024),
                          amdgpu_waves_per_eu(4)))
void fused_gcn(
    const float* __restrict__ x, const int* __restrict__ idx,
    const __hip_bfloat16* __restrict__ Wt1_,
    const __hip_bfloat16* __restrict__ Wt2_,
    const __hip_bfloat16* __restrict__ Wt3_,
    const float* __restrict__ b1, const float* __restrict__ b2,
    const float* __restrict__ b3,
    const float* __restrict__ gamma, const float* __restrict__ beta,
    float* __restrict__ out)
{
    __shared__ __align__(16) char LB[2 * PIPEB];       // 147456
    __shared__ int mlist0[MC2], mlist1[MC2];
    __shared__ int wcnt0[8], wcnt1[8];

    int tid = threadIdx.x;
    int w = tid >> 6;          // wave 0..15
    int lane = tid & 63;
    int quad = lane >> 4;
    int l15 = lane & 15;
    int p = w >> 3;            // pipeline 0/1
    int u = w & 7;             // wave role within pipeline (R17's "w")
    int g0 = blockIdx.x * 2;
    int g1 = g0 + 1;

    // ---- prologue: waves 0-7 scan idx once, classifying BOTH groups ----
    int* WS0 = (int*)LB;                 // 8 waves x WSLOT — aliases pipe0 RA
    int* WS1 = (int*)(LB + 8192);        // dead before first P0 write
    if (w < 8) {
        int slice = w * 625;
        int wc0 = 0, wc1 = 0;
        unsigned long long lowm = (1ull << lane) - 1ull;
#pragma unroll
        for (int b2i = 0; b2i < 2; ++b2i) {
            int4 v[5];
#pragma unroll
            for (int r = 0; r < 5; ++r) {
                int q = (b2i * 5 + r) * 64 + lane;
                v[r] = (q < 625) ? *(const int4*)&idx[(slice + q) * 4]
                                 : make_int4(-1, -1, -1, -1);
            }
#pragma unroll
            for (int r = 0; r < 5; ++r) {
                int j0 = (slice + (b2i * 5 + r) * 64 + lane) * 4;
                // group g0
                {
                    bool f0 = (v[r].x == g0), f1 = (v[r].y == g0);
                    bool f2 = (v[r].z == g0), f3 = (v[r].w == g0);
                    unsigned long long m0 = __ballot(f0), m1 = __ballot(f1);
                    unsigned long long m2 = __ballot(f2), m3 = __ballot(f3);
                    int pp = wc0 + __popcll(m0 & lowm) + __popcll(m1 & lowm)
                                 + __popcll(m2 & lowm) + __popcll(m3 & lowm);
                    int e0 = (int)f0, e1 = (int)f1, e2 = (int)f2;
                    if (f0 && pp < WSLOT)                WS0[w * WSLOT + pp] = j0;
                    if (f1 && pp + e0 < WSLOT)           WS0[w * WSLOT + pp + e0] = j0 + 1;
                    if (f2 && pp + e0 + e1 < WSLOT)      WS0[w * WSLOT + pp + e0 + e1] = j0 + 2;
                    if (f3 && pp + e0 + e1 + e2 < WSLOT) WS0[w * WSLOT + pp + e0 + e1 + e2] = j0 + 3;
                    wc0 += __popcll(m0) + __popcll(m1) + __popcll(m2) + __popcll(m3);
                }
                // group g1
                {
                    bool f0 = (v[r].x == g1), f1 = (v[r].y == g1);
                    bool f2 = (v[r].z == g1), f3 = (v[r].w == g1);
                    unsigned long long m0 = __ballot(f0), m1 = __ballot(f1);
                    unsigned long long m2 = __ballot(f2), m3 = __ballot(f3);
                    int pp = wc1 + __popcll(m0 & lowm) + __popcll(m1 & lowm)
                                 + __popcll(m2 & lowm) + __popcll(m3 & lowm);
                    int e0 = (int)f0, e1 = (int)f1, e2 = (int)f2;
                    if (f0 && pp < WSLOT)                WS1[w * WSLOT + pp] = j0;
                    if (f1 && pp + e0 < WSLOT)           WS1[w * WSLOT + pp + e0] = j0 + 1;
                    if (f2 && pp + e0 + e1 < WSLOT)      WS1[w * WSLOT + pp + e0 + e1] = j0 + 2;
                    if (f3 && pp + e0 + e1 + e2 < WSLOT) WS1[w * WSLOT + pp + e0 + e1 + e2] = j0 + 3;
                    wc1 += __popcll(m0) + __popcll(m1) + __popcll(m2) + __popcll(m3);
                }
            }
        }
        if (lane == 0) { wcnt0[w] = min(wc0, WSLOT); wcnt1[w] = min(wc1, WSLOT); }
    }
    __syncthreads();                                   // barrier #1: wcnt
    int cnt0 = 0, cnt1 = 0;
    {
        int pre0 = 0, pre1 = 0;
#pragma unroll
        for (int ww = 0; ww < 8; ++ww) {
            int c0 = wcnt0[ww], c1w = wcnt1[ww];
            if (ww < w) { pre0 += c0; pre1 += c1w; }
            cnt0 += c0; cnt1 += c1w;
        }
        cnt0 = min(cnt0, MC2); cnt1 = min(cnt1, MC2);
        if (w < 8) {
            int myc0 = wcnt0[w], myc1 = wcnt1[w];
            for (int k = lane; k < myc0; k += 64) {
                int dstp = pre0 + k;
                if (dstp < MC2) mlist0[dstp] = WS0[w * WSLOT + k];
            }
            for (int k = lane; k < myc1; k += 64) {
                int dstp = pre1 + k;
                if (dstp < MC2) mlist1[dstp] = WS1[w * WSLOT + k];
            }
        }
    }
    int cmax = max(cnt0, cnt1);
    if (cmax <= 0) return;

    float2 gmv = *(const float2*)&gamma[lane * 2];
    float2 btv = *(const float2*)&beta[lane * 2];
    // hoisted per-lane biases (indexed by scan-output feature = quad*4+r)
    float4 bb1[2], bb2[2], bb3;
#pragma unroll
    for (int i = 0; i < 2; ++i) {
        bb1[i] = *(const float4*)&b1[(2 * u + i) * 16 + quad * 4];
        bb2[i] = *(const float4*)&b2[(2 * u + i) * 16 + quad * 4];
    }
    bb3 = *(const float4*)&b3[u * 16 + quad * 4];

    __syncthreads();                                   // barrier #2: mlists ready, WS dead

    // pipeline-local bindings
    int mycnt = p ? cnt1 : cnt0;
    int* mylist = p ? mlist1 : mlist0;
    char* PB = LB + p * PIPEB;

    // lower-triangular-ones B-frag generator (verified R7..R17)
    auto ltfrag = [&](int nt, int k2) -> short8 {
        int thr = nt * 16 + l15 - k2 * 32 - quad * 8;
        short8 f;
#pragma unroll
        for (int e = 0; e < 8; ++e)
            f[e] = (e <= thr) ? (short)0x3F80 : (short)0;
        return f;
    };

    float c1[2][4], c2[2][4], c3[4];
#pragma unroll
    for (int r = 0; r < 4; ++r) {
        c1[0][r] = 0.f; c1[1][r] = 0.f;
        c2[0][r] = 0.f; c2[1][r] = 0.f;
        c3[r] = 0.f;
    }

    // chunk-loop-opaque weight pointers (LICM breaker — R13/R14 evidence)
    const short* wt1p = (const short*)Wt1_;
    const short* wt2p = (const short*)Wt2_;
    const short* wt3p = (const short*)Wt3_;

    for (int base = 0; base < cmax; base += 64) {
        asm("" : "+s"(wt1p), "+s"(wt2p), "+s"(wt3p));
        int mt = min(64, mycnt - base);                // may be <= 0 (idle pipeline)
        int par = (base >> 6) & 1;
        char* Rc = PB + (par ? REGB : 0);
        char* Rd = PB + (par ? 0 : REGB);
        short* T1 = (short*)Rc;
        short* T2 = (short*)Rc;
        short* T3 = (short*)Rc;
        float* F  = (float*)Rc;
        short* Yt = (short*)Rd;    // feat-major GEMM output (reused x3)

        float djn[4];
#pragma unroll
        for (int nt = 0; nt < 4; ++nt)
            djn[nt] = rsqrtf((float)(base + nt * 16 + l15 + 1));

        // ---- P0: x rows -> T1 = bf16(x * sd), node-major; reg-staged ----
        {
            int row = (lane >> 3) + 8 * u;            // 0..63
            int mr = base + row;
            int mi = (mr < mycnt) ? mr : (mycnt > 0 ? mycnt - 1 : 0);
            int nid = (mycnt > 0) ? mylist[mi] : 0;
            float sdr = rsqrtf((float)(mr + 1));
            const float* xp = x + (size_t)nid * D_IN + (lane & 7) * 4;
#pragma unroll
            for (int t = 0; t < 4; ++t) {
                float4 v = *(const float4*)(xp + t * 32);
                short4v o;
                o[0] = f2b(v.x * sdr); o[1] = f2b(v.y * sdr);
                o[2] = f2b(v.z * sdr); o[3] = f2b(v.w * sdr);
                *(short4v*)&T1[row * ST1 + (lane & 7) * 4 + t * 32] = o;
            }
        }
        __syncthreads();   // B1: T1 ready

        // ---- G1: Yt = (T1 @ W1^T) feat-major raw; 2 n-tiles/wave ----
        {
            floatx4 acc[4][2];
#pragma unroll
            for (int i = 0; i < 4; ++i) { acc[i][0] = (floatx4)0.0f; acc[i][1] = (floatx4)0.0f; }
#pragma unroll
            for (int kk = 0; kk < 4; ++kk) {          // K = 128
                short8 a4[4], bw[2];
#pragma unroll
                for (int i = 0; i < 4; ++i)
                    a4[i] = *(const short8*)&T1[(i * 16 + l15) * ST1 + kk * 32 + quad * 8];
#pragma unroll
                for (int nt = 0; nt < 2; ++nt)
                    bw[nt] = *(const short8*)&wt1p[((size_t)((u * 2 + nt) * 16 + l15)) * D_IN + kk * 32 + quad * 8];
#pragma unroll
                for (int i = 0; i < 4; ++i)
#pragma unroll
                    for (int nt = 0; nt < 2; ++nt)
                        acc[i][nt] = __builtin_amdgcn_mfma_f32_16x16x32_bf16(
                            a4[i], bw[nt], acc[i][nt], 0, 0, 0);
            }
#pragma unroll
            for (int i = 0; i < 4; ++i)
#pragma unroll
                for (int nt = 0; nt < 2; ++nt) {
                    short4v o4;
#pragma unroll
                    for (int r = 0; r < 4; ++r) o4[r] = f2b(acc[i][nt][r]);
                    *(short4v*)&Yt[((u * 2 + nt) * 16 + l15) * STY + i * 16 + quad * 4] = o4;
                }
        }
        __syncthreads();   // B2: Yt ready, T1 dead

        // ---- scan1: T2[j][c] = bf16(relu(dj*(c1+cumsum Yt)+b1)*dj); 2 tiles/wave
        {
            floatx4 acc[2][4];
#pragma unroll
            for (int i = 0; i < 2; ++i)
#pragma unroll
                for (int nt = 0; nt < 4; ++nt) acc[i][nt] = (floatx4)0.0f;
#pragma unroll
            for (int k2 = 0; k2 < 2; ++k2) {
                short8 af[2];
#pragma unroll
                for (int i = 0; i < 2; ++i)
                    af[i] = *(const short8*)&Yt[((2 * u + i) * 16 + l15) * STY + k2 * 32 + quad * 8];
#pragma unroll
                for (int nt = 0; nt < 4; ++nt) {
                    short8 lt = ltfrag(nt, k2);
#pragma unroll
                    for (int i = 0; i < 2; ++i)
                        acc[i][nt] = __builtin_amdgcn_mfma_f32_16x16x32_bf16(
                            af[i], lt, acc[i][nt], 0, 0, 0);
                }
            }
#pragma unroll
            for (int i = 0; i < 2; ++i) {
                float nc[4] = {0.f, 0.f, 0.f, 0.f};
#pragma unroll
                for (int nt = 0; nt < 4; ++nt) {
                    float tmp[4];
#pragma unroll
                    for (int r = 0; r < 4; ++r) tmp[r] = acc[i][nt][r] + c1[i][r];
                    if (nt == 3) {
#pragma unroll
                        for (int r = 0; r < 4; ++r) nc[r] = tmp[r];
                    }
                    short4v o4;
                    o4[0] = f2b(fmaxf(tmp[0] * djn[nt] + bb1[i].x, 0.0f) * djn[nt]);
                    o4[1] = f2b(fmaxf(tmp[1] * djn[nt] + bb1[i].y, 0.0f) * djn[nt]);
                    o4[2] = f2b(fmaxf(tmp[2] * djn[nt] + bb1[i].z, 0.0f) * djn[nt]);
                    o4[3] = f2b(fmaxf(tmp[3] * djn[nt] + bb1[i].w, 0.0f) * djn[nt]);
                    *(short4v*)&T2[(nt * 16 + l15) * ST2 + (2 * u + i) * 16 + quad * 4] = o4;
                }
#pragma unroll
                for (int r = 0; r < 4; ++r)
                    c1[i][r] = __shfl(nc[r], (lane & 48) + 15);
            }
        }
        __syncthreads();   // B3: T2 ready, Yt dead

        // ---- G2: Yt = (T2 @ W2^T) feat-major raw; 2 n-tiles/wave ----
        {
            floatx4 acc[4][2];
#pragma unroll
            for (int i = 0; i < 4; ++i) { acc[i][0] = (floatx4)0.0f; acc[i][1] = (floatx4)0.0f; }
#pragma unroll
            for (int kk = 0; kk < 8; ++kk) {          // K = 256
                short8 a4[4], bw[2];
#pragma unroll
                for (int i = 0; i < 4; ++i)
                    a4[i] = *(const short8*)&T2[(i * 16 + l15) * ST2 + kk * 32 + quad * 8];
#pragma unroll
                for (int nt = 0; nt < 2; ++nt)
                    bw[nt] = *(const short8*)&wt2p[((size_t)((u * 2 + nt) * 16 + l15)) * H1 + kk * 32 + quad * 8];
#pragma unroll
                for (int i = 0; i < 4; ++i)
#pragma unroll
                    for (int nt = 0; nt < 2; ++nt)
                        acc[i][nt] = __builtin_amdgcn_mfma_f32_16x16x32_bf16(
                            a4[i], bw[nt], acc[i][nt], 0, 0, 0);
            }
#pragma unroll
            for (int i = 0; i < 4; ++i)
#pragma unroll
                for (int nt = 0; nt < 2; ++nt) {
                    short4v o4;
#pragma unroll
                    for (int r = 0; r < 4; ++r) o4[r] = f2b(acc[i][nt][r]);
                    *(short4v*)&Yt[((u * 2 + nt) * 16 + l15) * STY + i * 16 + quad * 4] = o4;
                }
        }
        __syncthreads();   // B4: Yt ready, T2 dead

        // ---- scan2: T3[j][c] = bf16(relu(dj*(c2+cumsum Yt)+b2)*dj); 2 tiles/wave
        {
            floatx4 acc[2][4];
#pragma unroll
            for (int i = 0; i < 2; ++i)
#pragma unroll
                for (int nt = 0; nt < 4; ++nt) acc[i][nt] = (floatx4)0.0f;
#pragma unroll
            for (int k2 = 0; k2 < 2; ++k2) {
                short8 af[2];
#pragma unroll
                for (int i = 0; i < 2; ++i)
                    af[i] = *(const short8*)&Yt[((2 * u + i) * 16 + l15) * STY + k2 * 32 + quad * 8];
#pragma unroll
                for (int nt = 0; nt < 4; ++nt) {
                    short8 lt = ltfrag(nt, k2);
#pragma unroll
                    for (int i = 0; i < 2; ++i)
                        acc[i][nt] = __builtin_amdgcn_mfma_f32_16x16x32_bf16(
                            af[i], lt, acc[i][nt], 0, 0, 0);
                }
            }
#pragma unroll
            for (int i = 0; i < 2; ++i) {
                float nc[4] = {0.f, 0.f, 0.f, 0.f};
#pragma unroll
                for (int nt = 0; nt < 4; ++nt) {
                    float tmp[4];
#pragma unroll
                    for (int r = 0; r < 4; ++r) tmp[r] = acc[i][nt][r] + c2[i][r];
                    if (nt == 3) {
#pragma unroll
                        for (int r = 0; r < 4; ++r) nc[r] = tmp[r];
                    }
                    short4v o4;
                    o4[0] = f2b(fmaxf(tmp[0] * djn[nt] + bb2[i].x, 0.0f) * djn[nt]);
                    o4[1] = f2b(fmaxf(tmp[1] * djn[nt] + bb2[i].y, 0.0f) * djn[nt]);
                    o4[2] = f2b(fmaxf(tmp[2] * djn[nt] + bb2[i].z, 0.0f) * djn[nt]);
                    o4[3] = f2b(fmaxf(tmp[3] * djn[nt] + bb2[i].w, 0.0f) * djn[nt]);
                    *(short4v*)&T3[(nt * 16 + l15) * ST3 + (2 * u + i) * 16 + quad * 4] = o4;
                }
#pragma unroll
                for (int r = 0; r < 4; ++r)
                    c2[i][r] = __shfl(nc[r], (lane & 48) + 15);
            }
        }
        __syncthreads();   // B5: T3 ready, Yt dead

        // ---- G3: Yt = (T3 @ W3^T) feat-major raw; 1 n-tile/wave ----
        {
            floatx4 acc[4];
#pragma unroll
            for (int i = 0; i < 4; ++i) acc[i] = (floatx4)0.0f;
#pragma unroll
            for (int kk = 0; kk < 8; ++kk) {          // K = 256
                short8 bw = *(const short8*)&wt3p[((size_t)(u * 16 + l15)) * H2 + kk * 32 + quad * 8];
#pragma unroll
                for (int i = 0; i < 4; ++i) {
                    short8 a4 = *(const short8*)&T3[(i * 16 + l15) * ST3 + kk * 32 + quad * 8];
                    acc[i] = __builtin_amdgcn_mfma_f32_16x16x32_bf16(a4, bw, acc[i], 0, 0, 0);
                }
            }
#pragma unroll
            for (int i = 0; i < 4; ++i) {
                short4v o4;
#pragma unroll
                for (int r = 0; r < 4; ++r) o4[r] = f2b(acc[i][r]);
                *(short4v*)&Yt[(u * 16 + l15) * STY + i * 16 + quad * 4] = o4;
            }
        }
        __syncthreads();   // B6: Yt ready, T3 dead

        // ---- scan3: F[j][d] = relu(dj*(c3+cumsum Yt)+b3) fp32; 1 tile/wave
        {
            floatx4 acc[4];
#pragma unroll
            for (int nt = 0; nt < 4; ++nt) acc[nt] = (floatx4)0.0f;
#pragma unroll
            for (int k2 = 0; k2 < 2; ++k2) {
                short8 af = *(const short8*)&Yt[(u * 16 + l15) * STY + k2 * 32 + quad * 8];
#pragma unroll
                for (int nt = 0; nt < 4; ++nt)
                    acc[nt] = __builtin_amdgcn_mfma_f32_16x16x32_bf16(
                        af, ltfrag(nt, k2), acc[nt], 0, 0, 0);
            }
            float nc[4] = {0.f, 0.f, 0.f, 0.f};
#pragma unroll
            for (int nt = 0; nt < 4; ++nt) {
                float tmp[4];
#pragma unroll
                for (int r = 0; r < 4; ++r) tmp[r] = acc[nt][r] + c3[r];
                if (nt == 3) {
#pragma unroll
                    for (int r = 0; r < 4; ++r) nc[r] = tmp[r];
                }
                float4 o;
                o.x = fmaxf(tmp[0] * djn[nt] + bb3.x, 0.0f);
                o.y = fmaxf(tmp[1] * djn[nt] + bb3.y, 0.0f);
                o.z = fmaxf(tmp[2] * djn[nt] + bb3.z, 0.0f);
                o.w = fmaxf(tmp[3] * djn[nt] + bb3.w, 0.0f);
                *(float4*)&F[(nt * 16 + l15) * SF + u * 16 + quad * 4] = o;
            }
#pragma unroll
            for (int r = 0; r < 4; ++r)
                c3[r] = __shfl(nc[r], (lane & 48) + 15);
        }
        __syncthreads();   // B7: F ready, Yt dead

        // ---- LayerNorm rows -> out (8 waves/pipeline: rows u, u+8, ...) ----
        for (int r = u; r < mt; r += 8) {
            float2 v = *(const float2*)&F[r * SF + lane * 2];
            float s1 = v.x + v.y;
            float s2v = v.x * v.x + v.y * v.y;
#pragma unroll
            for (int off = 32; off > 0; off >>= 1) {
                s1 += __shfl_down(s1, off);
                s2v += __shfl_down(s2v, off);
            }
            s1 = __shfl(s1, 0);
            s2v = __shfl(s2v, 0);
            float mu = s1 * (1.0f / D_OUT);
            float var = s2v * (1.0f / D_OUT) - mu * mu;
            float rstd = rsqrtf(var + 1e-5f);
            float2 o;
            o.x = (v.x - mu) * rstd * gmv.x + btv.x;
            o.y = (v.y - mu) * rstd * gmv.y + btv.y;
            *(float2*)&out[(size_t)mylist[base + r] * D_OUT + lane * 2] = o;
        }
    }
}

// ---------------------------------------------------------------------------

extern "C" void kernel_launch(void* const* d_in, const int* in_sizes, int n_in,
                              void* d_out, int out_size, void* d_ws, size_t ws_size,
                              hipStream_t stream) {
    const float* x     = (const float*)d_in[0];
    const int*   idx   = (const int*)d_in[1];
    const float* W1    = (const float*)d_in[2];
    const float* b1    = (const float*)d_in[3];
    const float* W2    = (const float*)d_in[4];
    const float* b2    = (const float*)d_in[5];
    const float* W3    = (const float*)d_in[6];
    const float* b3    = (const float*)d_in[7];
    const float* gamma = (const float*)d_in[8];
    const float* beta  = (const float*)d_in[9];
    float* out = (float*)d_out;

    char* ws = (char*)d_ws;
    size_t off = 0;
    auto alloc = [&](size_t bytes) -> void* {
        void* p = (void*)(ws + off);
        off += (bytes + 255) & ~(size_t)255;
        return p;
    };
    __hip_bfloat16* Wt1 = (__hip_bfloat16*)alloc((size_t)D_IN * H1 * 2);
    __hip_bfloat16* Wt2 = (__hip_bfloat16*)alloc((size_t)H1 * H2 * 2);
    __hip_bfloat16* Wt3 = (__hip_bfloat16*)alloc((size_t)H2 * D_OUT * 2);

    wt_all<<<(WT_ELEMS + 255) / 256, 256, 0, stream>>>(
        W1, W2, W3, Wt1, Wt2, Wt3);

    fused_gcn<<<NG / 2, 1024, 0, stream>>>(
        x, idx, Wt1, Wt2, Wt3, b1, b2, b3, gamma, beta, out);
}

// Round 11
// 127.193 us; speedup vs baseline: 1.2070x; 1.2070x over previous
//
#include <hip/hip_runtime.h>
#include <hip/hip_bf16.h>

// Problem constants (GCN_66649302499531)
#define NN 20000
#define NG 400
#define D_IN 128
#define H1 256
#define H2 256
#define D_OUT 128
#define WT_ELEMS (D_IN * H1 + H1 * H2 + H2 * D_OUT)   // 131072
#define MCAP 1024   // member-list cap
#define WSLOT 256   // per-wave slice scratch cap (slice mean 6.25)
#define GRID0 256   // persistent grid; groups >= GRID0 are stolen

// LDS strides (elements)
#define STY 72      // Yt feat-major: 256 x 72 bf16 (64 nodes + 8 pad)
#define ST1 136     // T1 node-major: 64 x 128 bf16 (+8 pad)
#define ST2 264     // T2 node-major: 64 x 256 bf16 (+8 pad)
#define ST3 264     // T3 node-major
#define SF  132     // F  node-major: 64 x 128 fp32 (+4 pad)
#define REGB 36864

typedef __attribute__((ext_vector_type(8))) short short8;
typedef __attribute__((ext_vector_type(4))) short short4v;
typedef __attribute__((ext_vector_type(4))) float floatx4;

__device__ __forceinline__ short f2b(float f) {
    __hip_bfloat16 h = __float2bfloat16(f);
    return *(short*)&h;
}

// ---------------------------------------------------------------------------
// Weight transposes fp32 [K][N] -> bf16 [N][K], one launch.
// ---------------------------------------------------------------------------

__global__ __launch_bounds__(256) void wt_all(
    const float* __restrict__ W1, const float* __restrict__ W2,
    const float* __restrict__ W3, __hip_bfloat16* __restrict__ Wt1,
    __hip_bfloat16* __restrict__ Wt2, __hip_bfloat16* __restrict__ Wt3)
{
    int o = blockIdx.x * 256 + threadIdx.x;
    if (o < D_IN * H1) {
        int n = o / D_IN, k = o - n * D_IN;
        Wt1[o] = __float2bfloat16(W1[(size_t)k * H1 + n]);
    } else if (o < D_IN * H1 + H1 * H2) {
        int p = o - D_IN * H1;
        int n = p / H1, k = p - n * H1;
        Wt2[p] = __float2bfloat16(W2[(size_t)k * H2 + n]);
    } else if (o < WT_ELEMS) {
        int p = o - D_IN * H1 - H1 * H2;
        int n = p / H2, k = p - n * H2;
        Wt3[p] = __float2bfloat16(W3[(size_t)k * D_OUT + n]);
    }
}

// ---------------------------------------------------------------------------
// R26: persistent work-stealing wrapper around the VERIFIED R17 body.
// Grid 256 (one WG/CU): block processes group bid, then steals groups
// 256..399 via atomicAdd(gctr) (counter memset to 0 per launch). Only 256
// WGs pay issue latency (issue-rate model: dispatch ~= Nwg/r + L, r~11/us)
// while the 144 extra groups ride for free. Output deterministic: groups
// partition nodes -> disjoint out rows, steal order irrelevant.
// Per-group body verbatim R17 (53us, passed). Added: loop-top barrier
// (protects RA vs prev group's LN reads), LDS broadcast of stolen g,
// per-group carry reset, group-invariant biases hoisted.
// ---------------------------------------------------------------------------

__global__ __launch_bounds__(512) void fused_gcn(
    const float* __restrict__ x, const int* __restrict__ idx,
    const __hip_bfloat16* __restrict__ Wt1_,
    const __hip_bfloat16* __restrict__ Wt2_,
    const __hip_bfloat16* __restrict__ Wt3_,
    const float* __restrict__ b1, const float* __restrict__ b2,
    const float* __restrict__ b3,
    const float* __restrict__ gamma, const float* __restrict__ beta,
    float* __restrict__ out, int* __restrict__ gctr)
{
    __shared__ __align__(16) char RA[REGB];
    __shared__ __align__(16) char RB[REGB];
    __shared__ int mlist[MCAP];
    __shared__ int wcnt[8];
    __shared__ int gsh;

    int tid = threadIdx.x;
    int w = tid >> 6;          // wave 0..7
    int lane = tid & 63;
    int quad = lane >> 4;
    int l15 = lane & 15;

    // group-invariant per-lane constants (hoisted out of the group loop)
    float2 gmv = *(const float2*)&gamma[lane * 2];
    float2 btv = *(const float2*)&beta[lane * 2];
    float4 bb1a = *(const float4*)&b1[(2 * w + 0) * 16 + quad * 4];
    float4 bb1b = *(const float4*)&b1[(2 * w + 1) * 16 + quad * 4];
    float4 bb2a = *(const float4*)&b2[(2 * w + 0) * 16 + quad * 4];
    float4 bb2b = *(const float4*)&b2[(2 * w + 1) * 16 + quad * 4];
    float4 bb3  = *(const float4*)&b3[w * 16 + quad * 4];

    // lower-triangular-ones B-frag generator (verified R7..R17)
    auto ltfrag = [&](int nt, int k2) -> short8 {
        int thr = nt * 16 + l15 - k2 * 32 - quad * 8;
        short8 f;
#pragma unroll
        for (int e = 0; e < 8; ++e)
            f[e] = (e <= thr) ? (short)0x3F80 : (short)0;
        return f;
    };

    // chunk-loop-opaque weight pointers (LICM breaker — R13/R14 evidence)
    const short* wt1p = (const short*)Wt1_;
    const short* wt2p = (const short*)Wt2_;
    const short* wt3p = (const short*)Wt3_;

    int g = blockIdx.x;
    while (g < NG) {
        // protect RA (prev group's F read by LN) before WS writes; also
        // orders the gsh broadcast from the previous steal.
        __syncthreads();

        // ---- prologue: wave-parallel ordered compaction of group g ----
        int* WS = (int*)RA;   // aliases chunk-0 T1 — dead before first P0 write
        {
            int slice = w * 625;
            int wcount = 0;
            unsigned long long lowm = (1ull << lane) - 1ull;
#pragma unroll
            for (int b2i = 0; b2i < 2; ++b2i) {
                int4 v[5];
#pragma unroll
                for (int r = 0; r < 5; ++r) {
                    int q = (b2i * 5 + r) * 64 + lane;
                    v[r] = (q < 625) ? *(const int4*)&idx[(slice + q) * 4]
                                     : make_int4(-1, -1, -1, -1);
                }
#pragma unroll
                for (int r = 0; r < 5; ++r) {
                    bool f0 = (v[r].x == g), f1 = (v[r].y == g);
                    bool f2 = (v[r].z == g), f3 = (v[r].w == g);
                    unsigned long long m0 = __ballot(f0), m1 = __ballot(f1);
                    unsigned long long m2 = __ballot(f2), m3 = __ballot(f3);
                    int p = wcount + __popcll(m0 & lowm) + __popcll(m1 & lowm)
                                   + __popcll(m2 & lowm) + __popcll(m3 & lowm);
                    int j0 = (slice + (b2i * 5 + r) * 64 + lane) * 4;
                    int e0 = (int)f0, e1 = (int)f1, e2 = (int)f2;
                    if (f0 && p < WSLOT)                WS[w * WSLOT + p] = j0;
                    if (f1 && p + e0 < WSLOT)           WS[w * WSLOT + p + e0] = j0 + 1;
                    if (f2 && p + e0 + e1 < WSLOT)      WS[w * WSLOT + p + e0 + e1] = j0 + 2;
                    if (f3 && p + e0 + e1 + e2 < WSLOT) WS[w * WSLOT + p + e0 + e1 + e2] = j0 + 3;
                    wcount += __popcll(m0) + __popcll(m1) + __popcll(m2) + __popcll(m3);
                }
            }
            if (lane == 0) wcnt[w] = min(wcount, WSLOT);
        }
        __syncthreads();                                   // wcnt ready
        int cnt = 0;
        {
            int myprefix = 0;
#pragma unroll
            for (int ww = 0; ww < 8; ++ww) {
                int c = wcnt[ww];
                if (ww < w) myprefix += c;
                cnt += c;
            }
            cnt = min(cnt, MCAP);
            int myc = wcnt[w];
            for (int k = lane; k < myc; k += 64) {
                int dstp = myprefix + k;
                if (dstp < MCAP) mlist[dstp] = WS[w * WSLOT + k];
            }
        }

        if (cnt > 0) {
            __syncthreads();                               // mlist ready, WS dead

            float c1[2][4], c2[2][4], c3[4];
#pragma unroll
            for (int r = 0; r < 4; ++r) {
                c1[0][r] = 0.f; c1[1][r] = 0.f;
                c2[0][r] = 0.f; c2[1][r] = 0.f;
                c3[r] = 0.f;
            }
            float4 bb1[2] = {bb1a, bb1b};
            float4 bb2[2] = {bb2a, bb2b};

            for (int base = 0; base < cnt; base += 64) {
                asm("" : "+s"(wt1p), "+s"(wt2p), "+s"(wt3p));
                int mt = min(64, cnt - base);
                int par = (base >> 6) & 1;
                char* Rc = par ? RB : RA;
                char* Rd = par ? RA : RB;
                short* T1 = (short*)Rc;
                short* T2 = (short*)Rc;
                short* T3 = (short*)Rc;
                float* F  = (float*)Rc;
                short* Yt = (short*)Rd;    // feat-major GEMM output (reused x3)

                float djn[4];
#pragma unroll
                for (int nt = 0; nt < 4; ++nt)
                    djn[nt] = rsqrtf((float)(base + nt * 16 + l15 + 1));

                // ---- P0: x rows -> T1 = bf16(x * sd), node-major ----
                {
                    int row = (lane >> 3) + 8 * w;            // 0..63
                    int mr = base + row;
                    int nid = mlist[mr < cnt ? mr : cnt - 1];
                    float sdr = rsqrtf((float)(mr + 1));
                    const float* xp = x + (size_t)nid * D_IN + (lane & 7) * 4;
#pragma unroll
                    for (int t = 0; t < 4; ++t) {
                        float4 v = *(const float4*)(xp + t * 32);
                        short4v o;
                        o[0] = f2b(v.x * sdr); o[1] = f2b(v.y * sdr);
                        o[2] = f2b(v.z * sdr); o[3] = f2b(v.w * sdr);
                        *(short4v*)&T1[row * ST1 + (lane & 7) * 4 + t * 32] = o;
                    }
                }
                __syncthreads();   // B1: T1 ready

                // ---- G1: Yt = (T1 @ W1^T) feat-major raw; 2 n-tiles/wave ----
                {
                    floatx4 acc[4][2];
#pragma unroll
                    for (int i = 0; i < 4; ++i) { acc[i][0] = (floatx4)0.0f; acc[i][1] = (floatx4)0.0f; }
#pragma unroll
                    for (int kk = 0; kk < 4; ++kk) {          // K = 128
                        short8 a4[4], bw[2];
#pragma unroll
                        for (int i = 0; i < 4; ++i)
                            a4[i] = *(const short8*)&T1[(i * 16 + l15) * ST1 + kk * 32 + quad * 8];
#pragma unroll
                        for (int nt = 0; nt < 2; ++nt)
                            bw[nt] = *(const short8*)&wt1p[((size_t)((w * 2 + nt) * 16 + l15)) * D_IN + kk * 32 + quad * 8];
#pragma unroll
                        for (int i = 0; i < 4; ++i)
#pragma unroll
                            for (int nt = 0; nt < 2; ++nt)
                                acc[i][nt] = __builtin_amdgcn_mfma_f32_16x16x32_bf16(
                                    a4[i], bw[nt], acc[i][nt], 0, 0, 0);
                    }
#pragma unroll
                    for (int i = 0; i < 4; ++i)
#pragma unroll
                        for (int nt = 0; nt < 2; ++nt) {
                            short4v o4;
#pragma unroll
                            for (int r = 0; r < 4; ++r) o4[r] = f2b(acc[i][nt][r]);
                            *(short4v*)&Yt[((w * 2 + nt) * 16 + l15) * STY + i * 16 + quad * 4] = o4;
                        }
                }
                __syncthreads();   // B2: Yt ready, T1 dead

                // ---- scan1: T2 = bf16(relu(dj*(c1+cumsum Yt)+b1)*dj); 2 tiles/wave
                {
                    floatx4 acc[2][4];
#pragma unroll
                    for (int i = 0; i < 2; ++i)
#pragma unroll
                        for (int nt = 0; nt < 4; ++nt) acc[i][nt] = (floatx4)0.0f;
#pragma unroll
                    for (int k2 = 0; k2 < 2; ++k2) {
                        short8 af[2];
#pragma unroll
                        for (int i = 0; i < 2; ++i)
                            af[i] = *(const short8*)&Yt[((2 * w + i) * 16 + l15) * STY + k2 * 32 + quad * 8];
#pragma unroll
                        for (int nt = 0; nt < 4; ++nt) {
                            short8 lt = ltfrag(nt, k2);
#pragma unroll
                            for (int i = 0; i < 2; ++i)
                                acc[i][nt] = __builtin_amdgcn_mfma_f32_16x16x32_bf16(
                                    af[i], lt, acc[i][nt], 0, 0, 0);
                        }
                    }
#pragma unroll
                    for (int i = 0; i < 2; ++i) {
                        float nc[4] = {0.f, 0.f, 0.f, 0.f};
#pragma unroll
                        for (int nt = 0; nt < 4; ++nt) {
                            float tmp[4];
#pragma unroll
                            for (int r = 0; r < 4; ++r) tmp[r] = acc[i][nt][r] + c1[i][r];
                            if (nt == 3) {
#pragma unroll
                                for (int r = 0; r < 4; ++r) nc[r] = tmp[r];
                            }
                            short4v o4;
                            o4[0] = f2b(fmaxf(tmp[0] * djn[nt] + bb1[i].x, 0.0f) * djn[nt]);
                            o4[1] = f2b(fmaxf(tmp[1] * djn[nt] + bb1[i].y, 0.0f) * djn[nt]);
                            o4[2] = f2b(fmaxf(tmp[2] * djn[nt] + bb1[i].z, 0.0f) * djn[nt]);
                            o4[3] = f2b(fmaxf(tmp[3] * djn[nt] + bb1[i].w, 0.0f) * djn[nt]);
                            *(short4v*)&T2[(nt * 16 + l15) * ST2 + (2 * w + i) * 16 + quad * 4] = o4;
                        }
#pragma unroll
                        for (int r = 0; r < 4; ++r)
                            c1[i][r] = __shfl(nc[r], (lane & 48) + 15);
                    }
                }
                __syncthreads();   // B3: T2 ready, Yt dead

                // ---- G2: Yt = (T2 @ W2^T) feat-major raw; 2 n-tiles/wave ----
                {
                    floatx4 acc[4][2];
#pragma unroll
                    for (int i = 0; i < 4; ++i) { acc[i][0] = (floatx4)0.0f; acc[i][1] = (floatx4)0.0f; }
#pragma unroll
                    for (int kk = 0; kk < 8; ++kk) {          // K = 256
                        short8 a4[4], bw[2];
#pragma unroll
                        for (int i = 0; i < 4; ++i)
                            a4[i] = *(const short8*)&T2[(i * 16 + l15) * ST2 + kk * 32 + quad * 8];
#pragma unroll
                        for (int nt = 0; nt < 2; ++nt)
                            bw[nt] = *(const short8*)&wt2p[((size_t)((w * 2 + nt) * 16 + l15)) * H1 + kk * 32 + quad * 8];
#pragma unroll
                        for (int i = 0; i < 4; ++i)
#pragma unroll
                            for (int nt = 0; nt < 2; ++nt)
                                acc[i][nt] = __builtin_amdgcn_mfma_f32_16x16x32_bf16(
                                    a4[i], bw[nt], acc[i][nt], 0, 0, 0);
                    }
#pragma unroll
                    for (int i = 0; i < 4; ++i)
#pragma unroll
                        for (int nt = 0; nt < 2; ++nt) {
                            short4v o4;
#pragma unroll
                            for (int r = 0; r < 4; ++r) o4[r] = f2b(acc[i][nt][r]);
                            *(short4v*)&Yt[((w * 2 + nt) * 16 + l15) * STY + i * 16 + quad * 4] = o4;
                        }
                }
                __syncthreads();   // B4: Yt ready, T2 dead

                // ---- scan2: T3 = bf16(relu(dj*(c2+cumsum Yt)+b2)*dj); 2 tiles/wave
                {
                    floatx4 acc[2][4];
#pragma unroll
                    for (int i = 0; i < 2; ++i)
#pragma unroll
                        for (int nt = 0; nt < 4; ++nt) acc[i][nt] = (floatx4)0.0f;
#pragma unroll
                    for (int k2 = 0; k2 < 2; ++k2) {
                        short8 af[2];
#pragma unroll
                        for (int i = 0; i < 2; ++i)
                            af[i] = *(const short8*)&Yt[((2 * w + i) * 16 + l15) * STY + k2 * 32 + quad * 8];
#pragma unroll
                        for (int nt = 0; nt < 4; ++nt) {
                            short8 lt = ltfrag(nt, k2);
#pragma unroll
                            for (int i = 0; i < 2; ++i)
                                acc[i][nt] = __builtin_amdgcn_mfma_f32_16x16x32_bf16(
                                    af[i], lt, acc[i][nt], 0, 0, 0);
                        }
                    }
#pragma unroll
                    for (int i = 0; i < 2; ++i) {
                        float nc[4] = {0.f, 0.f, 0.f, 0.f};
#pragma unroll
                        for (int nt = 0; nt < 4; ++nt) {
                            float tmp[4];
#pragma unroll
                            for (int r = 0; r < 4; ++r) tmp[r] = acc[i][nt][r] + c2[i][r];
                            if (nt == 3) {
#pragma unroll
                                for (int r = 0; r < 4; ++r) nc[r] = tmp[r];
                            }
                            short4v o4;
                            o4[0] = f2b(fmaxf(tmp[0] * djn[nt] + bb2[i].x, 0.0f) * djn[nt]);
                            o4[1] = f2b(fmaxf(tmp[1] * djn[nt] + bb2[i].y, 0.0f) * djn[nt]);
                            o4[2] = f2b(fmaxf(tmp[2] * djn[nt] + bb2[i].z, 0.0f) * djn[nt]);
                            o4[3] = f2b(fmaxf(tmp[3] * djn[nt] + bb2[i].w, 0.0f) * djn[nt]);
                            *(short4v*)&T3[(nt * 16 + l15) * ST3 + (2 * w + i) * 16 + quad * 4] = o4;
                        }
#pragma unroll
                        for (int r = 0; r < 4; ++r)
                            c2[i][r] = __shfl(nc[r], (lane & 48) + 15);
                    }
                }
                __syncthreads();   // B5: T3 ready, Yt dead

                // ---- G3: Yt = (T3 @ W3^T) feat-major raw; 1 n-tile/wave ----
                {
                    floatx4 acc[4];
#pragma unroll
                    for (int i = 0; i < 4; ++i) acc[i] = (floatx4)0.0f;
#pragma unroll
                    for (int kk = 0; kk < 8; ++kk) {          // K = 256
                        short8 bw = *(const short8*)&wt3p[((size_t)(w * 16 + l15)) * H2 + kk * 32 + quad * 8];
#pragma unroll
                        for (int i = 0; i < 4; ++i) {
                            short8 a4 = *(const short8*)&T3[(i * 16 + l15) * ST3 + kk * 32 + quad * 8];
                            acc[i] = __builtin_amdgcn_mfma_f32_16x16x32_bf16(a4, bw, acc[i], 0, 0, 0);
                        }
                    }
#pragma unroll
                    for (int i = 0; i < 4; ++i) {
                        short4v o4;
#pragma unroll
                        for (int r = 0; r < 4; ++r) o4[r] = f2b(acc[i][r]);
                        *(short4v*)&Yt[(w * 16 + l15) * STY + i * 16 + quad * 4] = o4;
                    }
                }
                __syncthreads();   // B6: Yt ready, T3 dead

                // ---- scan3: F = relu(dj*(c3+cumsum Yt)+b3) fp32; 1 tile/wave
                {
                    floatx4 acc[4];
#pragma unroll
                    for (int nt = 0; nt < 4; ++nt) acc[nt] = (floatx4)0.0f;
#pragma unroll
                    for (int k2 = 0; k2 < 2; ++k2) {
                        short8 af = *(const short8*)&Yt[(w * 16 + l15) * STY + k2 * 32 + quad * 8];
#pragma unroll
                        for (int nt = 0; nt < 4; ++nt)
                            acc[nt] = __builtin_amdgcn_mfma_f32_16x16x32_bf16(
                                af, ltfrag(nt, k2), acc[nt], 0, 0, 0);
                    }
                    float nc[4] = {0.f, 0.f, 0.f, 0.f};
#pragma unroll
                    for (int nt = 0; nt < 4; ++nt) {
                        float tmp[4];
#pragma unroll
                        for (int r = 0; r < 4; ++r) tmp[r] = acc[nt][r] + c3[r];
                        if (nt == 3) {
#pragma unroll
                            for (int r = 0; r < 4; ++r) nc[r] = tmp[r];
                        }
                        float4 o;
                        o.x = fmaxf(tmp[0] * djn[nt] + bb3.x, 0.0f);
                        o.y = fmaxf(tmp[1] * djn[nt] + bb3.y, 0.0f);
                        o.z = fmaxf(tmp[2] * djn[nt] + bb3.z, 0.0f);
                        o.w = fmaxf(tmp[3] * djn[nt] + bb3.w, 0.0f);
                        *(float4*)&F[(nt * 16 + l15) * SF + w * 16 + quad * 4] = o;
                    }
#pragma unroll
                    for (int r = 0; r < 4; ++r)
                        c3[r] = __shfl(nc[r], (lane & 48) + 15);
                }
                __syncthreads();   // B7: F ready, Yt dead

                // ---- LayerNorm rows -> out ----
                for (int r = w; r < mt; r += 8) {
                    float2 v = *(const float2*)&F[r * SF + lane * 2];
                    float s1 = v.x + v.y;
                    float s2v = v.x * v.x + v.y * v.y;
#pragma unroll
                    for (int off = 32; off > 0; off >>= 1) {
                        s1 += __shfl_down(s1, off);
                        s2v += __shfl_down(s2v, off);
                    }
                    s1 = __shfl(s1, 0);
                    s2v = __shfl(s2v, 0);
                    float mu = s1 * (1.0f / D_OUT);
                    float var = s2v * (1.0f / D_OUT) - mu * mu;
                    float rstd = rsqrtf(var + 1e-5f);
                    float2 o;
                    o.x = (v.x - mu) * rstd * gmv.x + btv.x;
                    o.y = (v.y - mu) * rstd * gmv.y + btv.y;
                    *(float2*)&out[(size_t)mlist[base + r] * D_OUT + lane * 2] = o;
                }
            }
        }

        // ---- steal next group ----
        if (tid == 0) gsh = GRID0 + atomicAdd(gctr, 1);
        __syncthreads();          // gsh visible to all (RA still live: F reads
                                  // done? LN reads F before this point per-wave;
                                  // next loop-top barrier guards WS writes)
        g = gsh;
    }
}

// ---------------------------------------------------------------------------

extern "C" void kernel_launch(void* const* d_in, const int* in_sizes, int n_in,
                              void* d_out, int out_size, void* d_ws, size_t ws_size,
                              hipStream_t stream) {
    const float* x     = (const float*)d_in[0];
    const int*   idx   = (const int*)d_in[1];
    const float* W1    = (const float*)d_in[2];
    const float* b1    = (const float*)d_in[3];
    const float* W2    = (const float*)d_in[4];
    const float* b2    = (const float*)d_in[5];
    const float* W3    = (const float*)d_in[6];
    const float* b3    = (const float*)d_in[7];
    const float* gamma = (const float*)d_in[8];
    const float* beta  = (const float*)d_in[9];
    float* out = (float*)d_out;

    char* ws = (char*)d_ws;
    size_t off = 0;
    auto alloc = [&](size_t bytes) -> void* {
        void* p = (void*)(ws + off);
        off += (bytes + 255) & ~(size_t)255;
        return p;
    };
    __hip_bfloat16* Wt1 = (__hip_bfloat16*)alloc((size_t)D_IN * H1 * 2);
    __hip_bfloat16* Wt2 = (__hip_bfloat16*)alloc((size_t)H1 * H2 * 2);
    __hip_bfloat16* Wt3 = (__hip_bfloat16*)alloc((size_t)H2 * D_OUT * 2);
    int* gctr = (int*)alloc(256);

    wt_all<<<(WT_ELEMS + 255) / 256, 256, 0, stream>>>(
        W1, W2, W3, Wt1, Wt2, Wt3);
    hipMemsetAsync(gctr, 0, sizeof(int), stream);

    fused_gcn<<<GRID0, 512, 0, stream>>>(
        x, idx, Wt1, Wt2, Wt3, b1, b2, b3, gamma, beta, out, gctr);
}